// Round 6
// baseline (3240.390 us; speedup 1.0000x reference)
//
#include <hip/hip_runtime.h>
#include <hip/hip_bf16.h>
#include <stdint.h>

// ---------------------------------------------------------------------------
// coAttention: out = V_i + V_t + 0.5*V_c + 0.5*V_e
// V = softmax_n( sum_k tanh(feat@W)[n,k]*wp[K+k] + bias[n] ) @ feat.
// Query half of tanh-concat cancels in softmax -> 4 independent stages:
// c(N=20), e(30), i(49), t(128); B=256, D=1024, K=256.
// M = B*N: 5120/7680/12544/32768 -> 64-row tiles: 80/120/196/512 = 908.
//
// R5: replace reg-staged A (R0/R2/R4's shared stall: cvt->ds_write->vmcnt(0)
// ->barrier chain) with async global_load_lds of A as *f32* (width 16),
// double-buffered BK=32. Convert f32->bf16 AFTER ds_read, in-reg (VALU
// overlaps MFMA across waves, m114). LDS dest is linear (HW constraint);
// bank swizzle done by pre-swizzling the GLOBAL source chunk
// (lc = (lane&7)^(lane>>3)) and XOR-ing the read ((q*2)^(c16&7)) - rule #21.
// B stays frag-native bf16 from L2 (R4-proven), prefetched 1 iter ahead.
// ---------------------------------------------------------------------------

#define D_DIM 1024
#define K_OUT 256
#define BM 64
#define BK 32
#define NT 32   // K-tiles = 1024/32

typedef float f32x4 __attribute__((ext_vector_type(4)));
typedef short bf16x8 __attribute__((ext_vector_type(8)));
typedef unsigned short u16x8 __attribute__((ext_vector_type(8)));

static __device__ __forceinline__ unsigned short f2bf(float f) {
    return __builtin_bit_cast(unsigned short, __float2bfloat16(f));
}

// tanh(x) = 1 - 2/(exp(2x)+1); stable at +/-inf.
static __device__ __forceinline__ float fast_tanh(float x) {
    float e = __expf(2.0f * x);
    return 1.0f - 2.0f / (e + 1.0f);
}

// async global->LDS, 16 B per lane; LDS dest = wave-uniform base + lane*16.
static __device__ __forceinline__ void gll16(const float* g, void* lds) {
    __builtin_amdgcn_global_load_lds(
        (const __attribute__((address_space(1))) unsigned int*)g,
        (__attribute__((address_space(3))) unsigned int*)lds, 16, 0, 0);
}

// ---------------------------------------------------------------------------
// Kernel 1: W (f32 [1024][256]) -> frag-native bf16:
// ushort off = kblk*4096 + col*16 + half*8 + j, where k = kblk*16+half*8+j.
// ---------------------------------------------------------------------------
__global__ __launch_bounds__(256) void convert_wt(
    const float* __restrict__ w_c, const float* __restrict__ w_e,
    const float* __restrict__ w_i, const float* __restrict__ w_t,
    unsigned short* __restrict__ wtf)
{
    const float* wsel[4] = {w_c, w_e, w_i, w_t};
    const float* W = wsel[blockIdx.x];
    unsigned short* out = wtf + (size_t)blockIdx.x * (K_OUT * D_DIM);
    const int kb = blockIdx.y;          // 0..63
    const int t = threadIdx.x;          // col 0..255

    unsigned short tmp[16];
#pragma unroll
    for (int j = 0; j < 16; ++j)
        tmp[j] = f2bf(W[(size_t)(kb * 16 + j) * K_OUT + t]);   // coalesced over t

    u16x8 lo, hi;
#pragma unroll
    for (int j = 0; j < 8; ++j) { lo[j] = tmp[j]; hi[j] = tmp[8 + j]; }
    unsigned short* dst = out + (size_t)kb * 4096 + t * 16;
    *reinterpret_cast<u16x8*>(dst) = lo;
    *reinterpret_cast<u16x8*>(dst + 8) = hi;
}

// ---------------------------------------------------------------------------
// Kernel 2: fused logits GEMM, BM=64 x 256 cols, BK=32, 256 thr (4 waves,
// wave = 64 rows x 64 cols, mt=4 x nt=4, 16 MFMA/iter, 32 iters).
// ---------------------------------------------------------------------------
struct GemmStage {
    const float* feat;          // [M][1024] f32
    const unsigned short* wt;   // frag-native bf16, 256K ushorts
    const float* wp;            // [512] f32 (use [256..])
    float* s_out;               // [M]
    int blk_start;              // in 64-row tiles
};

__global__ __launch_bounds__(256, 3) void logits_gemm(
    GemmStage g0, GemmStage g1, GemmStage g2, GemmStage g3)
{
    __shared__ __align__(16) unsigned char As[2][BM * BK * 4];  // 2 x 8 KB f32
    __shared__ float partial[BM][4];

    const int bid = blockIdx.x;
    GemmStage st;
    if (bid < g1.blk_start) st = g0;
    else if (bid < g2.blk_start) st = g1;
    else if (bid < g3.blk_start) st = g2;
    else st = g3;
    const int m0 = (bid - st.blk_start) * BM;

    const int t = threadIdx.x;
    const int wv = t >> 6, lane = t & 63;
    const int q = lane >> 4, c16 = lane & 15;

    // ---- A staging via global_load_lds (linear LDS, pre-swizzled source) ----
    // slot s = wv*128 + j*64 + lane covers LDS 16B-chunk s: row=s>>3, pos=s&7.
    // stored pos p holds logical chunk p ^ (row&7); row&7 == lane>>3.
    const int srow = (lane >> 3);
    const int lc = (lane & 7) ^ srow;            // logical chunk to fetch
    const float* gs0 = st.feat + (size_t)(m0 + wv * 16 + srow) * D_DIM + lc * 4;
    const float* gs1 = gs0 + (size_t)8 * D_DIM;  // rows +8
    // wave-uniform LDS bases (byte): instr j of wave wv -> (wv*2+j)*1024
    const int lb0 = (wv * 2 + 0) * 1024;
    const int lb1 = (wv * 2 + 1) * 1024;

    // ---- ds_read offsets (byte, within one 8 KB buffer) ----
    // lane reads row = mt*16+c16, logical chunks q*2, q*2+1 (4 f32 each).
    int ofs0[4], ofs1[4];
#pragma unroll
    for (int mt = 0; mt < 4; ++mt) {
        const int row = mt * 16 + c16;
        ofs0[mt] = row * 128 + ((((q * 2)    ) ^ (c16 & 7)) << 4);
        ofs1[mt] = row * 128 + ((((q * 2) + 1) ^ (c16 & 7)) << 4);
    }

    // ---- B frag-native pointer: k = kt*32 + q*8 + j ----
    const unsigned short* bb = st.wt + (q >> 1) * 4096
                             + ((wv * 64 + c16) << 4) + (q & 1) * 8;

    float wpf[4];
#pragma unroll
    for (int nt = 0; nt < 4; ++nt) wpf[nt] = st.wp[K_OUT + wv * 64 + nt * 16 + c16];

    f32x4 acc[4][4];
#pragma unroll
    for (int i = 0; i < 4; ++i)
#pragma unroll
        for (int j = 0; j < 4; ++j) acc[i][j] = (f32x4){0.f, 0.f, 0.f, 0.f};

    u16x8 pb[2][4];

    // prologue: A(0) -> As[0] (async), B(0) -> pb[0]
    gll16(gs0, &As[0][lb0]);
    gll16(gs1, &As[0][lb1]);
#pragma unroll
    for (int nt = 0; nt < 4; ++nt)
        pb[0][nt] = *reinterpret_cast<const u16x8*>(bb + nt * 256);
    __syncthreads();   // drains vmcnt -> As[0] ready

#pragma unroll 1
    for (int kt = 0; kt < NT; ++kt) {
        const int cur = kt & 1, nxt = cur ^ 1;
        // ---- issue next tile's loads first (hide under compute) ----
        if (kt + 1 < NT) {
            const float* g0 = gs0 + (kt + 1) * BK;
            gll16(g0, &As[nxt][lb0]);
            gll16(g0 + (size_t)8 * D_DIM, &As[nxt][lb1]);
            const unsigned short* bk = bb + (size_t)(kt + 1) * 8192;
#pragma unroll
            for (int nt = 0; nt < 4; ++nt)
                pb[nxt][nt] = *reinterpret_cast<const u16x8*>(bk + nt * 256);
        }
        // ---- ds_read f32 A-frags, cvt to bf16, MFMA ----
        const unsigned char* buf = As[cur];
#pragma unroll
        for (int mt = 0; mt < 4; ++mt) {
            f32x4 r0 = *reinterpret_cast<const f32x4*>(&buf[ofs0[mt]]);
            f32x4 r1 = *reinterpret_cast<const f32x4*>(&buf[ofs1[mt]]);
            u16x8 au;
#pragma unroll
            for (int j = 0; j < 4; ++j) { au[j] = f2bf(r0[j]); au[4 + j] = f2bf(r1[j]); }
            const bf16x8 af = __builtin_bit_cast(bf16x8, au);
#pragma unroll
            for (int nt = 0; nt < 4; ++nt)
                acc[mt][nt] = __builtin_amdgcn_mfma_f32_16x16x32_bf16(
                    af, __builtin_bit_cast(bf16x8, pb[cur][nt]), acc[mt][nt], 0, 0, 0);
        }
        __syncthreads();   // next buffer's async loads done; this buffer's reads done
    }

    // ---- epilogue: tanh * wp2, reduce cols -> s_out ----
    // C/D 16x16: col = c16 (+wv*64+nt*16), row = q*4 + reg (+mt*16)
#pragma unroll
    for (int mt = 0; mt < 4; ++mt) {
#pragma unroll
        for (int rg = 0; rg < 4; ++rg) {
            float v = 0.f;
#pragma unroll
            for (int nt = 0; nt < 4; ++nt)
                v += fast_tanh(acc[mt][nt][rg]) * wpf[nt];
            v += __shfl_xor(v, 1);
            v += __shfl_xor(v, 2);
            v += __shfl_xor(v, 4);
            v += __shfl_xor(v, 8);
            if (c16 == 0) partial[mt * 16 + q * 4 + rg][wv] = v;
        }
    }
    __syncthreads();
    if (t < BM)
        st.s_out[m0 + t] = partial[t][0] + partial[t][1] + partial[t][2] + partial[t][3];
}

// ---------------------------------------------------------------------------
// Kernel 3: per (b, stage): softmax over N logits (+bias), then V = P @ feat.
// ---------------------------------------------------------------------------
struct PVStage {
    const float* s;       // [B*N]
    const float* bias;    // [N]
    const float* feat;    // [B*N][1024]
    float* v_out;         // [B][1024]
    int N;
};

__global__ __launch_bounds__(256) void softmax_pv(
    PVStage p0, PVStage p1, PVStage p2, PVStage p3)
{
    PVStage st = (blockIdx.y == 0) ? p0 : (blockIdx.y == 1) ? p1
               : (blockIdx.y == 2) ? p2 : p3;
    const int b = blockIdx.x, t = threadIdx.x;
    const int N = st.N;

    __shared__ float P[128];
    __shared__ float inv_s;

    if (t < N) P[t] = st.s[b * N + t] + st.bias[t];
    __syncthreads();
    if (t < 64) {
        float m = -3.4e38f;
        for (int n = t; n < N; n += 64) m = fmaxf(m, P[n]);
#pragma unroll
        for (int sh = 32; sh; sh >>= 1) m = fmaxf(m, __shfl_xor(m, sh));
        float ssum = 0.f;
        for (int n = t; n < N; n += 64) { float e = __expf(P[n] - m); P[n] = e; ssum += e; }
#pragma unroll
        for (int sh = 32; sh; sh >>= 1) ssum += __shfl_xor(ssum, sh);
        if (t == 0) inv_s = 1.0f / ssum;
    }
    __syncthreads();
    const float inv = inv_s;

    f32x4 accv = (f32x4){0.f, 0.f, 0.f, 0.f};
    const float* fb = st.feat + (size_t)b * N * D_DIM + t * 4;
    for (int n = 0; n < N; ++n) {
        f32x4 f = *reinterpret_cast<const f32x4*>(fb + (size_t)n * D_DIM);
        accv += (P[n] * inv) * f;
    }
    *reinterpret_cast<f32x4*>(&st.v_out[(size_t)b * D_DIM + t * 4]) = accv;
}

// ---------------------------------------------------------------------------
// Kernel 4: out = V_i + V_t + 0.5*V_c + 0.5*V_e
// ---------------------------------------------------------------------------
__global__ __launch_bounds__(256) void combine_out(
    const float* __restrict__ vc, const float* __restrict__ ve,
    const float* __restrict__ vi, const float* __restrict__ vt,
    float* __restrict__ out)
{
    const int i = (blockIdx.x * 256 + threadIdx.x) * 4;
    f32x4 a = *reinterpret_cast<const f32x4*>(vi + i);
    f32x4 bb = *reinterpret_cast<const f32x4*>(vt + i);
    f32x4 c = *reinterpret_cast<const f32x4*>(vc + i);
    f32x4 e = *reinterpret_cast<const f32x4*>(ve + i);
    *reinterpret_cast<f32x4*>(out + i) = a + bb + 0.5f * c + 0.5f * e;
}

// ---------------------------------------------------------------------------
extern "C" void kernel_launch(void* const* d_in, const int* in_sizes, int n_in,
                              void* d_out, int out_size, void* d_ws, size_t ws_size,
                              hipStream_t stream)
{
    const float* ifeature = (const float*)d_in[0];   // (256,49,1024)
    const float* tfeature = (const float*)d_in[1];   // (256,128,1024)
    const float* cfeature = (const float*)d_in[2];   // (256,20,1024)
    const float* efeature = (const float*)d_in[3];   // (256,30,1024)
    const float* w_Vc = (const float*)d_in[5];
    const float* w_Pc = (const float*)d_in[6];
    const float* b_Pc = (const float*)d_in[7];
    const float* w_Ve = (const float*)d_in[8];
    const float* w_Pe = (const float*)d_in[9];
    const float* b_Pe = (const float*)d_in[10];
    const float* w_Vi = (const float*)d_in[11];
    const float* w_Pi = (const float*)d_in[13];
    const float* b_Pi = (const float*)d_in[14];
    const float* w_Vt = (const float*)d_in[16];
    const float* w_Pt = (const float*)d_in[17];
    const float* b_Pt = (const float*)d_in[18];

    // workspace layout (~7 MB)
    char* ws = (char*)d_ws;
    unsigned short* wtf = (unsigned short*)ws;                // 4 x 512KB bf16
    float* s_c = (float*)(ws + 2u * 1024 * 1024);             // 5120
    float* s_e = s_c + 5120;                                  // 7680
    float* s_i = s_e + 7680;                                  // 12544
    float* s_t = s_i + 12544;                                 // 32768
    float* v_c = (float*)(ws + 3u * 1024 * 1024);             // 4 x 1MB
    float* v_e = v_c + 256 * 1024;
    float* v_i = v_e + 256 * 1024;
    float* v_t = v_i + 256 * 1024;

    convert_wt<<<dim3(4, 64), 256, 0, stream>>>(w_Vc, w_Ve, w_Vi, w_Vt, wtf);

    // 64-row tiles: c=80, e=120, i=196, t=512 -> 908 blocks
    GemmStage g0{cfeature, wtf,          w_Pc, s_c, 0};
    GemmStage g1{efeature, wtf + 262144, w_Pe, s_e, 80};
    GemmStage g2{ifeature, wtf + 524288, w_Pi, s_i, 200};
    GemmStage g3{tfeature, wtf + 786432, w_Pt, s_t, 396};
    logits_gemm<<<908, 256, 0, stream>>>(g0, g1, g2, g3);

    PVStage p0{s_c, b_Pc, cfeature, v_c, 20};
    PVStage p1{s_e, b_Pe, efeature, v_e, 30};
    PVStage p2{s_i, b_Pi, ifeature, v_i, 49};
    PVStage p3{s_t, b_Pt, tfeature, v_t, 128};
    softmax_pv<<<dim3(256, 4), 256, 0, stream>>>(p0, p1, p2, p3);

    combine_out<<<256, 256, 0, stream>>>(v_c, v_e, v_i, v_t, (float*)d_out);
}

// Round 7
// 101.852 us; speedup vs baseline: 31.8146x; 31.8146x over previous
//
#include <hip/hip_runtime.h>
#include <hip/hip_bf16.h>
#include <stdint.h>

// ---------------------------------------------------------------------------
// coAttention: out = V_i + V_t + 0.5*V_c + 0.5*V_e
// V = softmax_n( sum_k tanh(feat@W)[n,k]*wp[K+k] + bias[n] ) @ feat.
// Query half of tanh-concat cancels in softmax -> 4 independent stages:
// c(N=20), e(30), i(49), t(128); B=256, D=1024, K=256.
// M = B*N: 5120/7680/12544/32768 -> 64-row tiles: 80/120/196/512 = 908.
//
// R6: Little's-law fix. Achieved BW has scaled linearly with resident waves
// (R0/R4 11w->1.2TB/s, R2 21w->2.2TB/s) because the load queue drains every
// iter. Now: 8 waves/block (512thr, 16 waves/CU resident via VGPR<=128) AND
// depth-2 reg prefetch (T14 issue-early/write-late: A(kt+1) written to LDS
// was issued 2 bodies ago -> its vmcnt wait is free; A(kt+3) issued after).
// One barrier per body (ring-2 LDS). B frag-native from L2 (R4-proven).
// NO global_load_lds (R5: compiler waterfalled it, 30x regression).
// ---------------------------------------------------------------------------

#define D_DIM 1024
#define K_OUT 256
#define BM 64
#define BK 64
#define NT 16   // K-tiles = 1024/64

typedef float f32x4 __attribute__((ext_vector_type(4)));
typedef short bf16x8 __attribute__((ext_vector_type(8)));
typedef unsigned short u16x8 __attribute__((ext_vector_type(8)));

static __device__ __forceinline__ unsigned short f2bf(float f) {
    return __builtin_bit_cast(unsigned short, __float2bfloat16(f));
}

// tanh(x) = 1 - 2/(exp(2x)+1); stable at +/-inf.
static __device__ __forceinline__ float fast_tanh(float x) {
    float e = __expf(2.0f * x);
    return 1.0f - 2.0f / (e + 1.0f);
}

// ---------------------------------------------------------------------------
// Kernel 1: W (f32 [1024][256]) -> frag-native bf16:
// ushort off = kblk*4096 + col*16 + half*8 + j, where k = kblk*16+half*8+j.
// ---------------------------------------------------------------------------
__global__ __launch_bounds__(256) void convert_wt(
    const float* __restrict__ w_c, const float* __restrict__ w_e,
    const float* __restrict__ w_i, const float* __restrict__ w_t,
    unsigned short* __restrict__ wtf)
{
    const float* wsel[4] = {w_c, w_e, w_i, w_t};
    const float* W = wsel[blockIdx.x];
    unsigned short* out = wtf + (size_t)blockIdx.x * (K_OUT * D_DIM);
    const int kb = blockIdx.y;          // 0..63
    const int t = threadIdx.x;          // col 0..255

    unsigned short tmp[16];
#pragma unroll
    for (int j = 0; j < 16; ++j)
        tmp[j] = f2bf(W[(size_t)(kb * 16 + j) * K_OUT + t]);   // coalesced over t

    u16x8 lo, hi;
#pragma unroll
    for (int j = 0; j < 8; ++j) { lo[j] = tmp[j]; hi[j] = tmp[8 + j]; }
    unsigned short* dst = out + (size_t)kb * 4096 + t * 16;
    *reinterpret_cast<u16x8*>(dst) = lo;
    *reinterpret_cast<u16x8*>(dst + 8) = hi;
}

// ---------------------------------------------------------------------------
// Kernel 2: fused logits GEMM, BM=64 x 256 cols, BK=64, 512 thr = 8 waves.
// Wave wv: rows 0..63 (mt=4), cols wv*32..+31 (nt=2). 16 MFMA/wave/body.
// ---------------------------------------------------------------------------
struct GemmStage {
    const float* feat;          // [M][1024] f32
    const unsigned short* wt;   // frag-native bf16, 256K ushorts
    const float* wp;            // [512] f32 (use [256..])
    float* s_out;               // [M]
    int blk_start;              // in 64-row tiles
};

__global__ __launch_bounds__(512, 4) void logits_gemm(
    GemmStage g0, GemmStage g1, GemmStage g2, GemmStage g3)
{
    __shared__ __align__(16) unsigned char As[2][BM * 128];  // 2 x 8 KB bf16
    __shared__ float partial[BM][8];

    const int bid = blockIdx.x;
    GemmStage st;
    if (bid < g1.blk_start) st = g0;
    else if (bid < g2.blk_start) st = g1;
    else if (bid < g3.blk_start) st = g2;
    else st = g3;
    const int m0 = (bid - st.blk_start) * BM;

    const int t = threadIdx.x;
    const int wv = t >> 6, lane = t & 63;
    const int q = lane >> 4, c16 = lane & 15;

    // ---- A staging: thread -> (row r = t>>3, pos p = t&7) ----
    // LDS position (r,p) holds logical 16B chunk p^(r&7); so fetch global
    // chunk lc = p^(r&7) (8 f32 = 32B) and ds_write at linear byte t*16.
    const int r = t >> 3, p = t & 7;
    const int lc = p ^ (r & 7);
    const float* aptr = st.feat + (size_t)(m0 + r) * D_DIM + lc * 8;
    const int wofs = r * 128 + p * 16;

    // ---- ds_read offsets: row = mt*16+c16, logical chunk ks*4+q ----
    int rofs[4][2];
#pragma unroll
    for (int mt = 0; mt < 4; ++mt)
#pragma unroll
        for (int ks = 0; ks < 2; ++ks)
            rofs[mt][ks] = (mt * 16 + c16) * 128 + ((((ks * 4 + q)) ^ (c16 & 7)) << 4);

    // ---- B frag-native: k = kt*64 + ks*32 + q*8 + j ----
    // off = (kt*4 + ks*2 + (q>>1))*4096 + col*16 + (q&1)*8, col = wv*32+nt*16+c16
    const unsigned short* bb = st.wt + (size_t)(q >> 1) * 4096
                             + ((wv * 32 + c16) << 4) + (q & 1) * 8;

    float wpf[2];
#pragma unroll
    for (int nt = 0; nt < 2; ++nt) wpf[nt] = st.wp[K_OUT + wv * 32 + nt * 16 + c16];

    f32x4 acc[4][2];
#pragma unroll
    for (int i = 0; i < 4; ++i)
#pragma unroll
        for (int j = 0; j < 2; ++j) acc[i][j] = (f32x4){0.f, 0.f, 0.f, 0.f};

    // two named A prefetch sets (rule #20: no runtime-indexed reg arrays)
    f32x4 sa0, sa1, sb0, sb1;

    // ---- prologue: A0 -> buf0 (exposed wait, once); issue A1->sa, A2->sb ----
    sa0 = *reinterpret_cast<const f32x4*>(aptr);
    sa1 = *reinterpret_cast<const f32x4*>(aptr + 4);
    {
        u16x8 o;
#pragma unroll
        for (int j = 0; j < 4; ++j) { o[j] = f2bf(sa0[j]); o[4 + j] = f2bf(sa1[j]); }
        *reinterpret_cast<u16x8*>(&As[0][wofs]) = o;
    }
    sa0 = *reinterpret_cast<const f32x4*>(aptr + 64);
    sa1 = *reinterpret_cast<const f32x4*>(aptr + 68);
    sb0 = *reinterpret_cast<const f32x4*>(aptr + 128);
    sb1 = *reinterpret_cast<const f32x4*>(aptr + 132);
    __syncthreads();

#define GEMM_BODY(KT, BUFC, BUFN, S0, S1)                                      \
    {                                                                          \
        const int kt_ = (KT);                                                  \
        u16x8 rb[2][2];                                                        \
        const unsigned short* bk = bb + (size_t)kt_ * 16384;                   \
        _Pragma("unroll")                                                      \
        for (int ks = 0; ks < 2; ++ks)                                         \
            _Pragma("unroll")                                                  \
            for (int nt = 0; nt < 2; ++nt)                                     \
                rb[ks][nt] = *reinterpret_cast<const u16x8*>(                  \
                    bk + ks * 8192 + nt * 256);                                \
        _Pragma("unroll")                                                      \
        for (int ks = 0; ks < 2; ++ks) {                                       \
            bf16x8 af[4];                                                      \
            _Pragma("unroll")                                                  \
            for (int mt = 0; mt < 4; ++mt)                                     \
                af[mt] = *reinterpret_cast<const bf16x8*>(                     \
                    &As[BUFC][rofs[mt][ks]]);                                  \
            _Pragma("unroll")                                                  \
            for (int mt = 0; mt < 4; ++mt)                                     \
                _Pragma("unroll")                                              \
                for (int nt = 0; nt < 2; ++nt)                                 \
                    acc[mt][nt] = __builtin_amdgcn_mfma_f32_16x16x32_bf16(     \
                        af[mt], __builtin_bit_cast(bf16x8, rb[ks][nt]),        \
                        acc[mt][nt], 0, 0, 0);                                 \
        }                                                                      \
        if (kt_ + 1 < NT) {                                                    \
            u16x8 o;                                                           \
            _Pragma("unroll")                                                  \
            for (int j = 0; j < 4; ++j) {                                      \
                o[j] = f2bf(S0[j]); o[4 + j] = f2bf(S1[j]);                    \
            }                                                                  \
            *reinterpret_cast<u16x8*>(&As[BUFN][wofs]) = o;                    \
            if (kt_ + 3 < NT) {                                                \
                S0 = *reinterpret_cast<const f32x4*>(aptr + (kt_ + 3) * 64);   \
                S1 = *reinterpret_cast<const f32x4*>(aptr + (kt_ + 3) * 64 + 4);\
            }                                                                  \
        }                                                                      \
        __syncthreads();                                                       \
    }

#pragma unroll 1
    for (int k2 = 0; k2 < NT; k2 += 2) {
        GEMM_BODY(k2,     0, 1, sa0, sa1)   // even tile: read buf0, write buf1
        GEMM_BODY(k2 + 1, 1, 0, sb0, sb1)   // odd tile:  read buf1, write buf0
    }
#undef GEMM_BODY

    // ---- epilogue: tanh * wp2, reduce cols -> s_out ----
    // C/D 16x16: col = c16 (+wv*32+nt*16), row = q*4 + rg (+mt*16)
#pragma unroll
    for (int mt = 0; mt < 4; ++mt) {
#pragma unroll
        for (int rg = 0; rg < 4; ++rg) {
            float v = 0.f;
#pragma unroll
            for (int nt = 0; nt < 2; ++nt)
                v += fast_tanh(acc[mt][nt][rg]) * wpf[nt];
            v += __shfl_xor(v, 1);
            v += __shfl_xor(v, 2);
            v += __shfl_xor(v, 4);
            v += __shfl_xor(v, 8);
            if (c16 == 0) partial[mt * 16 + q * 4 + rg][wv] = v;
        }
    }
    __syncthreads();
    if (t < BM) {
        float v = 0.f;
#pragma unroll
        for (int w = 0; w < 8; ++w) v += partial[t][w];
        st.s_out[m0 + t] = v;
    }
}

// ---------------------------------------------------------------------------
// Kernel 3: per (b, stage): softmax over N logits (+bias), then V = P @ feat.
// ---------------------------------------------------------------------------
struct PVStage {
    const float* s;       // [B*N]
    const float* bias;    // [N]
    const float* feat;    // [B*N][1024]
    float* v_out;         // [B][1024]
    int N;
};

__global__ __launch_bounds__(256) void softmax_pv(
    PVStage p0, PVStage p1, PVStage p2, PVStage p3)
{
    PVStage st = (blockIdx.y == 0) ? p0 : (blockIdx.y == 1) ? p1
               : (blockIdx.y == 2) ? p2 : p3;
    const int b = blockIdx.x, t = threadIdx.x;
    const int N = st.N;

    __shared__ float P[128];
    __shared__ float inv_s;

    if (t < N) P[t] = st.s[b * N + t] + st.bias[t];
    __syncthreads();
    if (t < 64) {
        float m = -3.4e38f;
        for (int n = t; n < N; n += 64) m = fmaxf(m, P[n]);
#pragma unroll
        for (int sh = 32; sh; sh >>= 1) m = fmaxf(m, __shfl_xor(m, sh));
        float ssum = 0.f;
        for (int n = t; n < N; n += 64) { float e = __expf(P[n] - m); P[n] = e; ssum += e; }
#pragma unroll
        for (int sh = 32; sh; sh >>= 1) ssum += __shfl_xor(ssum, sh);
        if (t == 0) inv_s = 1.0f / ssum;
    }
    __syncthreads();
    const float inv = inv_s;

    f32x4 accv = (f32x4){0.f, 0.f, 0.f, 0.f};
    const float* fb = st.feat + (size_t)b * N * D_DIM + t * 4;
    for (int n = 0; n < N; ++n) {
        f32x4 f = *reinterpret_cast<const f32x4*>(fb + (size_t)n * D_DIM);
        accv += (P[n] * inv) * f;
    }
    *reinterpret_cast<f32x4*>(&st.v_out[(size_t)b * D_DIM + t * 4]) = accv;
}

// ---------------------------------------------------------------------------
// Kernel 4: out = V_i + V_t + 0.5*V_c + 0.5*V_e
// ---------------------------------------------------------------------------
__global__ __launch_bounds__(256) void combine_out(
    const float* __restrict__ vc, const float* __restrict__ ve,
    const float* __restrict__ vi, const float* __restrict__ vt,
    float* __restrict__ out)
{
    const int i = (blockIdx.x * 256 + threadIdx.x) * 4;
    f32x4 a = *reinterpret_cast<const f32x4*>(vi + i);
    f32x4 bb = *reinterpret_cast<const f32x4*>(vt + i);
    f32x4 c = *reinterpret_cast<const f32x4*>(vc + i);
    f32x4 e = *reinterpret_cast<const f32x4*>(ve + i);
    *reinterpret_cast<f32x4*>(out + i) = a + bb + 0.5f * c + 0.5f * e;
}

// ---------------------------------------------------------------------------
extern "C" void kernel_launch(void* const* d_in, const int* in_sizes, int n_in,
                              void* d_out, int out_size, void* d_ws, size_t ws_size,
                              hipStream_t stream)
{
    const float* ifeature = (const float*)d_in[0];   // (256,49,1024)
    const float* tfeature = (const float*)d_in[1];   // (256,128,1024)
    const float* cfeature = (const float*)d_in[2];   // (256,20,1024)
    const float* efeature = (const float*)d_in[3];   // (256,30,1024)
    const float* w_Vc = (const float*)d_in[5];
    const float* w_Pc = (const float*)d_in[6];
    const float* b_Pc = (const float*)d_in[7];
    const float* w_Ve = (const float*)d_in[8];
    const float* w_Pe = (const float*)d_in[9];
    const float* b_Pe = (const float*)d_in[10];
    const float* w_Vi = (const float*)d_in[11];
    const float* w_Pi = (const float*)d_in[13];
    const float* b_Pi = (const float*)d_in[14];
    const float* w_Vt = (const float*)d_in[16];
    const float* w_Pt = (const float*)d_in[17];
    const float* b_Pt = (const float*)d_in[18];

    // workspace layout (~7 MB)
    char* ws = (char*)d_ws;
    unsigned short* wtf = (unsigned short*)ws;                // 4 x 512KB bf16
    float* s_c = (float*)(ws + 2u * 1024 * 1024);             // 5120
    float* s_e = s_c + 5120;                                  // 7680
    float* s_i = s_e + 7680;                                  // 12544
    float* s_t = s_i + 12544;                                 // 32768
    float* v_c = (float*)(ws + 3u * 1024 * 1024);             // 4 x 1MB
    float* v_e = v_c + 256 * 1024;
    float* v_i = v_e + 256 * 1024;
    float* v_t = v_i + 256 * 1024;

    convert_wt<<<dim3(4, 64), 256, 0, stream>>>(w_Vc, w_Ve, w_Vi, w_Vt, wtf);

    // 64-row tiles: c=80, e=120, i=196, t=512 -> 908 blocks
    GemmStage g0{cfeature, wtf,          w_Pc, s_c, 0};
    GemmStage g1{efeature, wtf + 262144, w_Pe, s_e, 80};
    GemmStage g2{ifeature, wtf + 524288, w_Pi, s_i, 200};
    GemmStage g3{tfeature, wtf + 786432, w_Pt, s_t, 396};
    logits_gemm<<<908, 512, 0, stream>>>(g0, g1, g2, g3);

    PVStage p0{s_c, b_Pc, cfeature, v_c, 20};
    PVStage p1{s_e, b_Pe, efeature, v_e, 30};
    PVStage p2{s_i, b_Pi, ifeature, v_i, 49};
    PVStage p3{s_t, b_Pt, tfeature, v_t, 128};
    softmax_pv<<<dim3(256, 4), 256, 0, stream>>>(p0, p1, p2, p3);

    combine_out<<<256, 256, 0, stream>>>(v_c, v_e, v_i, v_t, (float*)d_out);
}